// Round 5
// baseline (985.135 us; speedup 1.0000x reference)
//
#include <hip/hip_runtime.h>

// LSTM: SEQ=4096, BATCH=4096, IN=2, HID=8, fp32.
// R11 = R9 structure + packed dots + 2 waves/SIMD.
//  - layout: 16 lanes/batch, lane l16 = hf*8+u; half0 owns rows (i,g~) of
//    unit u, half1 owns (f,o). 3 bank-masked ror8 DPPs exchange {gf,go2,i*g~};
//    c/h updated in all lanes (h replicated by construction). [R9, verified]
//  - dots: R10's packed split-dot. P_m = (h_{u^m}, h_{u^m^7}) built by
//    1 HMIR + 3 pair quad-perms (7 DPP total); each row dot = 1 pk init +
//    4 pk_fma + 1 add. 10 pk_fma replaces R9's 20 scalar fma.
//    Per-wave issue/step ~160 cy (trans 6x16 + VALU ~32x2), was ~207.
//  - geometry: 512-thread blocks, grid 128 -> 2 waves/SIMD on 128 CUs.
//    2x160=320 < R9 wall 376, so the partner wave absorbs the ~170cy of
//    unhidden dependency latency (R9 at 2/SIMD would NOT have: 2x207>376).
// Numerics identical to R6-R10: rows pre-scaled by -log2e (-2log2e for g~),
// c kept in scaled space c' = -2*log2e*c, sigmoid/tanh via exp2+rcp only.

#define SEQ   4096
#define BATCH 4096
#define PF    8

#define DPP_X1   0xB1  // quad_perm [1,0,3,2] : lane ^ 1
#define DPP_X2   0x4E  // quad_perm [2,3,0,1] : lane ^ 2
#define DPP_X3   0x1B  // quad_perm [3,2,1,0] : lane ^ 3
#define DPP_HMIR 0x141 // row_half_mirror     : lane ^ 7 (within 8-lane half)
#define DPP_ROR8 0x128 // row_ror:8           : lane ^ 8 (within 16-lane row)

typedef float v2f __attribute__((ext_vector_type(2)));

template<int CTRL>
__device__ __forceinline__ float rot(float v) {
    int i = __builtin_bit_cast(int, v);
    int r = __builtin_amdgcn_update_dpp(0, i, CTRL, 0xf, 0xf, true);
    return __builtin_bit_cast(float, r);
}
template<int CTRL>
__device__ __forceinline__ v2f dpp2(v2f v) {
    v2f r; r.x = rot<CTRL>(v.x); r.y = rot<CTRL>(v.y); return r;
}
// ror8 with bank-masked merge: lanes in enabled BANKS receive src[l^8],
// disabled banks keep 'oldv'. banks 0,1 = lanes 0-7 of each 16-row.
template<int BANKS>
__device__ __forceinline__ float ror8_keep(float oldv, float src) {
    int o = __builtin_bit_cast(int, oldv);
    int s = __builtin_bit_cast(int, src);
    int r = __builtin_amdgcn_update_dpp(o, s, DPP_ROR8, 0xf, BANKS, false);
    return __builtin_bit_cast(float, r);
}
__device__ __forceinline__ v2f vfma(v2f a, v2f b, v2f c) {
    return __builtin_elementwise_fma(a, b, c);
}

__global__ __launch_bounds__(512, 1) void lstm_kernel(
    const float* __restrict__ x,    // (SEQ, BATCH, 2)
    const float* __restrict__ h0,   // (1, BATCH, 8)
    const float* __restrict__ c0,   // (1, BATCH, 8)
    const float* __restrict__ Wih,  // (32, 2)
    const float* __restrict__ Whh,  // (32, 8)
    const float* __restrict__ bih,  // (32)
    const float* __restrict__ bhh,  // (32)
    float* __restrict__ out)        // (1, BATCH, 8)
{
    const int tid = threadIdx.x;
    const int l16 = tid & 15;
    const int u   = l16 & 7;         // unit 0..7
    const int hf  = l16 >> 3;        // 0: rows (i,g~)   1: rows (f,o)
    const int b   = blockIdx.x * 32 + (tid >> 4);

    const int row0 = hf * 8 + u;      // i-row (0..7)  or f-row (8..15)
    const int row1 = 16 + row0;       // g~-row (16..23) or o-row (24..31)

    const float L2E = 1.4426950408889634f;
    const float n2L = -2.0f * L2E;
    // pre-activation scales folded into weights:
    //   sigmoid rows (i,f,o): -L2E     tanh row (g~): -2*L2E
    const float smul0 = -L2E;
    const float smul1 = hf ? -L2E : n2L;
    // act0 = r0*tm0:        i -> -2L2E*sigma (scaled-c form)   f -> sigma
    // act1 = r1*2 + addc1:  g~ -> tanh                         o -> 2*sigma
    const float tm0   = hf ? 1.0f : n2L;
    const float addc1 = hf ? 0.0f : -1.0f;

    // weights paired for split-dot: pair m covers columns (u^m, u^m^7)
    const float* wr0 = Whh + row0 * 8;
    const float* wr1 = Whh + row1 * 8;
    v2f W0[4], W1[4];
#pragma unroll
    for (int m = 0; m < 4; ++m) {
        const int ka = u ^ m, kb = ka ^ 7;
        W0[m] = (v2f){ wr0[ka], wr0[kb] } * smul0;
        W1[m] = (v2f){ wr1[ka], wr1[kb] } * smul1;
    }
    const v2f WX0 = (v2f){ Wih[2 * row0], Wih[2 * row0 + 1] } * smul0;
    const v2f WX1 = (v2f){ Wih[2 * row1], Wih[2 * row1 + 1] } * smul1;
    const v2f B0  = { (bih[row0] + bhh[row0]) * smul0, 0.0f };
    const v2f B1  = { (bih[row1] + bhh[row1]) * smul1, 0.0f };

    // state: c in scaled space c' = -2*L2E*c; maintained validly in ALL lanes
    float c = c0[b * 8 + u] * n2L;
    float h = h0[b * 8 + u];

    const float2* __restrict__ xp2 = (const float2*)x;
    float2 xb[PF];
#pragma unroll
    for (int p = 0; p < PF; ++p) xb[p] = xp2[p * BATCH + b];

    for (int s = 0; s < SEQ; s += PF) {
#pragma unroll
        for (int p = 0; p < PF; ++p) {
            const float2 xc = xb[p];
            const int sn = (s + p + PF) & (SEQ - 1);   // uniform wrap
            xb[p] = xp2[sn * BATCH + b];
            const v2f xv = { xc.x, xc.y };

            // ---- h-gather: P_m = (h_{u^m}, h_{u^m^7}); 7 DPPs total
            v2f P0; P0.x = h; P0.y = rot<DPP_HMIR>(h);
            const v2f P1 = dpp2<DPP_X1>(P0);
            const v2f P2 = dpp2<DPP_X2>(P0);
            const v2f P3 = dpp2<DPP_X3>(P0);

            // ---- two packed split-dots (one per owned row), 5 pk each
            v2f a0 = vfma(xv, WX0, B0);
            v2f a1 = vfma(xv, WX1, B1);
            a0 = vfma(P0, W0[0], a0);  a1 = vfma(P0, W1[0], a1);
            a0 = vfma(P1, W0[1], a0);  a1 = vfma(P1, W1[1], a1);
            a0 = vfma(P2, W0[2], a0);  a1 = vfma(P2, W1[2], a1);
            a0 = vfma(P3, W0[3], a0);  a1 = vfma(P3, W1[3], a1);
            const float pre0 = a0.x + a0.y;            // already scaled
            const float pre1 = a1.x + a1.y;

            // ---- activations (two independent trans chains)
            const float e0 = __builtin_amdgcn_exp2f(pre0);
            const float e1 = __builtin_amdgcn_exp2f(pre1);
            const float r0 = __builtin_amdgcn_rcpf(e0 + 1.0f);
            const float r1 = __builtin_amdgcn_rcpf(e1 + 1.0f);
            const float act0 = r0 * tm0;                        // gi | gf
            const float act1 = __builtin_fmaf(r1, 2.0f, addc1); // gg | go2

            // ---- local product + 3 bank-masked ror8 exchanges
            const float pp  = act0 * act1;                // half0: gi*gg
            const float gf  = ror8_keep<0x3>(act0, act0); // all: sigma_f
            const float go2 = ror8_keep<0x3>(act1, act1); // all: 2*sigma_o
            const float ig  = ror8_keep<0xC>(pp, pp);     // all: gi*gg

            // ---- c/h update, valid in ALL lanes (h replicated by constr.)
            c = __builtin_fmaf(gf, c, ig);             // scaled-c recurrence
            const float e2 = __builtin_amdgcn_exp2f(c);
            const float r2 = __builtin_amdgcn_rcpf(e2 + 1.0f);
            h = __builtin_fmaf(go2, r2, go2 * -0.5f);  // h = 2sig*r - sig
        }
    }

    if (!hf) out[b * 8 + u] = h;
}

extern "C" void kernel_launch(void* const* d_in, const int* in_sizes, int n_in,
                              void* d_out, int out_size, void* d_ws, size_t ws_size,
                              hipStream_t stream) {
    const float* x   = (const float*)d_in[0];
    const float* h0  = (const float*)d_in[1];
    const float* c0  = (const float*)d_in[2];
    const float* Wih = (const float*)d_in[3];
    const float* Whh = (const float*)d_in[4];
    const float* bih = (const float*)d_in[5];
    const float* bhh = (const float*)d_in[6];
    float* out = (float*)d_out;

    dim3 grid(BATCH / 32);   // 128 blocks -> 1 block/CU on 128 CUs
    dim3 block(512);         // 8 waves/block -> 2 waves/SIMD (latency partner)
    hipLaunchKernelGGL(lstm_kernel, grid, block, 0, stream,
                       x, h0, c0, Wih, Whh, bih, bhh, out);
}

// Round 6
// 746.406 us; speedup vs baseline: 1.3198x; 1.3198x over previous
//
#include <hip/hip_runtime.h>

// LSTM: SEQ=4096, BATCH=4096, IN=2, HID=8, fp32.
// R12 = R11 packed math at R9 full-chip geometry + masked-tanh trims.
//  - geometry: grid 256 x block 256 -> 1024 waves = 1 wave/SIMD on ALL 256
//    CUs. (R11's only real bug: its 128-block grid idled half the chip.
//    At 16 lanes/batch, full chip <=> 4 batches/SIMD <=> 1 wave/SIMD.)
//  - layout: lane l16 = hf*8+u; half0 owns rows (i,g~) of unit u, half1
//    owns (f,o). [R9, verified]
//  - dots: packed split-dot, P_m = (h_{u^m}, h_{u^m^7}), 7 DPP + 10
//    v_pk_fma_f32 + 2 combine adds. [R11, verified numerically]
//  - NEW: c/h update EXEC-MASKED to hf==0 (32/64 lanes): the 2 recurrence
//    trans ops run at half lane-occupancy (trans pipe ~4 lanes/cy -> ~half
//    issue cost; R6's SFU-occupancy evidence). h re-broadcast by 1 ror8.
//  - NEW: ig exchange DROPPED -- c is updated only where pp=gi*gg already
//    lives (hf=0). Cross-lane ops stay at 3 ror8 + 7 gather DPPs.
//  - init pk_fmas (h-independent) hoisted before the DPP tree to pad the
//    h-write -> DPP-read hazard window.
// Numerics identical to R6-R11: rows pre-scaled by -log2e (-2log2e for g~),
// c kept in scaled space c' = -2*log2e*c, sigmoid/tanh via exp2+rcp only.

#define SEQ   4096
#define BATCH 4096
#define PF    8

#define DPP_X1   0xB1  // quad_perm [1,0,3,2] : lane ^ 1
#define DPP_X2   0x4E  // quad_perm [2,3,0,1] : lane ^ 2
#define DPP_X3   0x1B  // quad_perm [3,2,1,0] : lane ^ 3
#define DPP_HMIR 0x141 // row_half_mirror     : lane ^ 7 (within 8-lane half)
#define DPP_ROR8 0x128 // row_ror:8           : lane ^ 8 (within 16-lane row)

typedef float v2f __attribute__((ext_vector_type(2)));

template<int CTRL>
__device__ __forceinline__ float rot(float v) {
    int i = __builtin_bit_cast(int, v);
    int r = __builtin_amdgcn_update_dpp(0, i, CTRL, 0xf, 0xf, true);
    return __builtin_bit_cast(float, r);
}
template<int CTRL>
__device__ __forceinline__ v2f dpp2(v2f v) {
    v2f r; r.x = rot<CTRL>(v.x); r.y = rot<CTRL>(v.y); return r;
}
// ror8 with bank-masked merge: lanes in enabled BANKS receive src[l^8],
// disabled banks keep 'oldv'. banks 0,1 = lanes 0-7 of each 16-lane row.
template<int BANKS>
__device__ __forceinline__ float ror8_keep(float oldv, float src) {
    int o = __builtin_bit_cast(int, oldv);
    int s = __builtin_bit_cast(int, src);
    int r = __builtin_amdgcn_update_dpp(o, s, DPP_ROR8, 0xf, BANKS, false);
    return __builtin_bit_cast(float, r);
}
__device__ __forceinline__ v2f vfma(v2f a, v2f b, v2f c) {
    return __builtin_elementwise_fma(a, b, c);
}

__global__ __launch_bounds__(256, 1) void lstm_kernel(
    const float* __restrict__ x,    // (SEQ, BATCH, 2)
    const float* __restrict__ h0,   // (1, BATCH, 8)
    const float* __restrict__ c0,   // (1, BATCH, 8)
    const float* __restrict__ Wih,  // (32, 2)
    const float* __restrict__ Whh,  // (32, 8)
    const float* __restrict__ bih,  // (32)
    const float* __restrict__ bhh,  // (32)
    float* __restrict__ out)        // (1, BATCH, 8)
{
    const int tid = threadIdx.x;
    const int l16 = tid & 15;
    const int u   = l16 & 7;         // unit 0..7
    const int hf  = l16 >> 3;        // 0: rows (i,g~)   1: rows (f,o)
    const int b   = blockIdx.x * 16 + (tid >> 4);

    const int row0 = hf * 8 + u;      // i-row (0..7)  or f-row (8..15)
    const int row1 = 16 + row0;       // g~-row (16..23) or o-row (24..31)

    const float L2E = 1.4426950408889634f;
    const float n2L = -2.0f * L2E;
    // pre-activation scales folded into weights:
    //   sigmoid rows (i,f,o): -L2E     tanh row (g~): -2*L2E
    const float smul0 = -L2E;
    const float smul1 = hf ? -L2E : n2L;
    // act0 = r0*tm0:        i -> -2L2E*sigma (scaled-c form)   f -> sigma
    // act1 = r1*2 + addc1:  g~ -> tanh                         o -> 2*sigma
    const float tm0   = hf ? 1.0f : n2L;
    const float addc1 = hf ? 0.0f : -1.0f;

    // weights paired for split-dot: pair m covers columns (u^m, u^m^7)
    const float* wr0 = Whh + row0 * 8;
    const float* wr1 = Whh + row1 * 8;
    v2f W0[4], W1[4];
#pragma unroll
    for (int m = 0; m < 4; ++m) {
        const int ka = u ^ m, kb = ka ^ 7;
        W0[m] = (v2f){ wr0[ka], wr0[kb] } * smul0;
        W1[m] = (v2f){ wr1[ka], wr1[kb] } * smul1;
    }
    const v2f WX0 = (v2f){ Wih[2 * row0], Wih[2 * row0 + 1] } * smul0;
    const v2f WX1 = (v2f){ Wih[2 * row1], Wih[2 * row1 + 1] } * smul1;
    const v2f B0  = { (bih[row0] + bhh[row0]) * smul0, 0.0f };
    const v2f B1  = { (bih[row1] + bhh[row1]) * smul1, 0.0f };

    // state: c in scaled space c' = -2*L2E*c (valid in hf=0 lanes only);
    // h replicated to all lanes via the post-update ror8 broadcast
    float c = c0[b * 8 + u] * n2L;
    float h = h0[b * 8 + u];

    const float2* __restrict__ xp2 = (const float2*)x;
    float2 xb[PF];
#pragma unroll
    for (int p = 0; p < PF; ++p) xb[p] = xp2[p * BATCH + b];

    for (int s = 0; s < SEQ; s += PF) {
#pragma unroll
        for (int p = 0; p < PF; ++p) {
            const float2 xc = xb[p];
            const int sn = (s + p + PF) & (SEQ - 1);   // uniform wrap
            xb[p] = xp2[sn * BATCH + b];
            const v2f xv = { xc.x, xc.y };

            // ---- h-independent init first (pads h-write -> DPP hazard)
            v2f a0 = vfma(xv, WX0, B0);
            v2f a1 = vfma(xv, WX1, B1);

            // ---- h-gather: P_m = (h_{u^m}, h_{u^m^7}); 7 DPPs total
            v2f P0; P0.x = h; P0.y = rot<DPP_HMIR>(h);
            const v2f P1 = dpp2<DPP_X1>(P0);
            const v2f P2 = dpp2<DPP_X2>(P0);
            const v2f P3 = dpp2<DPP_X3>(P0);

            // ---- two packed split-dots (one per owned row), 4 pk_fma each
            a0 = vfma(P0, W0[0], a0);  a1 = vfma(P0, W1[0], a1);
            a0 = vfma(P1, W0[1], a0);  a1 = vfma(P1, W1[1], a1);
            a0 = vfma(P2, W0[2], a0);  a1 = vfma(P2, W1[2], a1);
            a0 = vfma(P3, W0[3], a0);  a1 = vfma(P3, W1[3], a1);
            const float pre0 = a0.x + a0.y;            // already scaled
            const float pre1 = a1.x + a1.y;

            // ---- activations (two independent trans chains, full wave)
            const float e0 = __builtin_amdgcn_exp2f(pre0);
            const float e1 = __builtin_amdgcn_exp2f(pre1);
            const float r0 = __builtin_amdgcn_rcpf(e0 + 1.0f);
            const float r1 = __builtin_amdgcn_rcpf(e1 + 1.0f);
            const float act0 = r0 * tm0;                        // gi | gf
            const float act1 = __builtin_fmaf(r1, 2.0f, addc1); // gg | go2

            // ---- exchanges: gf, go2 to hf=0 (pp stays local; no ig ror8)
            const float pp  = act0 * act1;                // hf0: gi*gg
            const float gf  = ror8_keep<0x3>(act0, act0); // hf0 gets sigma_f
            const float go2 = ror8_keep<0x3>(act1, act1); // hf0 gets 2*sig_o

            // ---- c/h update MASKED to hf==0 (trans at half occupancy)
            if (!hf) {
                c = __builtin_fmaf(gf, c, pp);          // scaled-c recurrence
                const float e2 = __builtin_amdgcn_exp2f(c);
                const float r2 = __builtin_amdgcn_rcpf(e2 + 1.0f);
                h = go2 * (r2 - 0.5f);                  // h = 2sig*r - sig
            }
            // re-broadcast h to hf=1 lanes (they need it for the gather)
            h = ror8_keep<0xC>(h, h);
        }
    }

    if (!hf) out[b * 8 + u] = h;
}

extern "C" void kernel_launch(void* const* d_in, const int* in_sizes, int n_in,
                              void* d_out, int out_size, void* d_ws, size_t ws_size,
                              hipStream_t stream) {
    const float* x   = (const float*)d_in[0];
    const float* h0  = (const float*)d_in[1];
    const float* c0  = (const float*)d_in[2];
    const float* Wih = (const float*)d_in[3];
    const float* Whh = (const float*)d_in[4];
    const float* bih = (const float*)d_in[5];
    const float* bhh = (const float*)d_in[6];
    float* out = (float*)d_out;

    dim3 grid(BATCH / 16);   // 256 blocks -> 1 block/CU on all 256 CUs
    dim3 block(256);         // 4 waves/block -> 1 wave/SIMD (full chip)
    hipLaunchKernelGGL(lstm_kernel, grid, block, 0, stream,
                       x, h0, c0, Wih, Whh, bih, bhh, out);
}

// Round 7
// 651.969 us; speedup vs baseline: 1.5110x; 1.1448x over previous
//
#include <hip/hip_runtime.h>

// LSTM: SEQ=4096, BATCH=4096, IN=2, HID=8, fp32.
// R13 = issue-floor grind + trans-gap filling at the verified full-chip
// geometry (grid 256 x block 256 = 1024 waves = 1 wave/SIMD).
//  - layout: lane l16 = hf*8+u; hf0 owns rows (i,g~), hf1 owns (f,o). [R9]
//  - dots: packed split-dot, pairs P_m=(h_{u^m}, h_{u^m^7}), 7 DPP +
//    8 pk_fma + 2 hadds. [R11/R12, verified]
//  - ALL-LANE c/h (no exec mask): removes saveexec SALU chains and the
//    h-rebroadcast DPP from the serial tail; ig ror8 returns (issues
//    off-path). R12 proved masking bought ~nothing (198 vs 207 issue).
//  - gap-filling: next-step x-init accumulators (h-independent) and the
//    x prefetch load are placed in the exp2/rcp latency shadows; ngo =
//    -0.5*go2 precomputed in the c-exp2 shadow so the post-rcp tail is
//    one fma.
// Numerics identical to R6-R12: rows pre-scaled by -log2e (-2log2e for
// g~), c in scaled space c' = -2*log2e*c, sigmoid/tanh via exp2+rcp only.

#define SEQ   4096
#define BATCH 4096
#define PF    8

#define DPP_X1   0xB1  // quad_perm [1,0,3,2] : lane ^ 1
#define DPP_X2   0x4E  // quad_perm [2,3,0,1] : lane ^ 2
#define DPP_X3   0x1B  // quad_perm [3,2,1,0] : lane ^ 3
#define DPP_HMIR 0x141 // row_half_mirror     : lane ^ 7 (within 8-lane half)
#define DPP_ROR8 0x128 // row_ror:8           : lane ^ 8 (within 16-lane row)

typedef float v2f __attribute__((ext_vector_type(2)));

template<int CTRL>
__device__ __forceinline__ float rot(float v) {
    int i = __builtin_bit_cast(int, v);
    int r = __builtin_amdgcn_update_dpp(0, i, CTRL, 0xf, 0xf, true);
    return __builtin_bit_cast(float, r);
}
template<int CTRL>
__device__ __forceinline__ v2f dpp2(v2f v) {
    v2f r; r.x = rot<CTRL>(v.x); r.y = rot<CTRL>(v.y); return r;
}
// ror8 with bank-masked merge: lanes in enabled BANKS receive src[l^8],
// disabled banks keep 'oldv'. banks 0,1 = lanes 0-7 of each 16-lane row.
template<int BANKS>
__device__ __forceinline__ float ror8_keep(float oldv, float src) {
    int o = __builtin_bit_cast(int, oldv);
    int s = __builtin_bit_cast(int, src);
    int r = __builtin_amdgcn_update_dpp(o, s, DPP_ROR8, 0xf, BANKS, false);
    return __builtin_bit_cast(float, r);
}
__device__ __forceinline__ v2f vfma(v2f a, v2f b, v2f c) {
    return __builtin_elementwise_fma(a, b, c);
}

__global__ __launch_bounds__(256, 1) void lstm_kernel(
    const float* __restrict__ x,    // (SEQ, BATCH, 2)
    const float* __restrict__ h0,   // (1, BATCH, 8)
    const float* __restrict__ c0,   // (1, BATCH, 8)
    const float* __restrict__ Wih,  // (32, 2)
    const float* __restrict__ Whh,  // (32, 8)
    const float* __restrict__ bih,  // (32)
    const float* __restrict__ bhh,  // (32)
    float* __restrict__ out)        // (1, BATCH, 8)
{
    const int tid = threadIdx.x;
    const int l16 = tid & 15;
    const int u   = l16 & 7;         // unit 0..7
    const int hf  = l16 >> 3;        // 0: rows (i,g~)   1: rows (f,o)
    const int b   = blockIdx.x * 16 + (tid >> 4);

    const int row0 = hf * 8 + u;      // i-row (0..7)  or f-row (8..15)
    const int row1 = 16 + row0;       // g~-row (16..23) or o-row (24..31)

    const float L2E = 1.4426950408889634f;
    const float n2L = -2.0f * L2E;
    // pre-activation scales folded into weights:
    //   sigmoid rows (i,f,o): -L2E     tanh row (g~): -2*L2E
    const float smul0 = -L2E;
    const float smul1 = hf ? -L2E : n2L;
    // act0 = r0*tm0:        i -> -2L2E*sigma (scaled-c form)   f -> sigma
    // act1 = r1*2 + addc1:  g~ -> tanh                         o -> 2*sigma
    const float tm0   = hf ? 1.0f : n2L;
    const float addc1 = hf ? 0.0f : -1.0f;

    // weights paired for split-dot: pair m covers columns (u^m, u^m^7)
    const float* wr0 = Whh + row0 * 8;
    const float* wr1 = Whh + row1 * 8;
    v2f W0[4], W1[4];
#pragma unroll
    for (int m = 0; m < 4; ++m) {
        const int ka = u ^ m, kb = ka ^ 7;
        W0[m] = (v2f){ wr0[ka], wr0[kb] } * smul0;
        W1[m] = (v2f){ wr1[ka], wr1[kb] } * smul1;
    }
    const v2f WX0 = (v2f){ Wih[2 * row0], Wih[2 * row0 + 1] } * smul0;
    const v2f WX1 = (v2f){ Wih[2 * row1], Wih[2 * row1 + 1] } * smul1;
    const v2f B0  = { (bih[row0] + bhh[row0]) * smul0, 0.0f };
    const v2f B1  = { (bih[row1] + bhh[row1]) * smul1, 0.0f };

    // state: c in scaled space c' = -2*L2E*c; valid in ALL lanes (no mask)
    float c = c0[b * 8 + u] * n2L;
    float h = h0[b * 8 + u];

    const float2* __restrict__ xp2 = (const float2*)x;
    float2 xb[PF];
#pragma unroll
    for (int p = 0; p < PF; ++p) xb[p] = xp2[p * BATCH + b];

    // carried next-step init accumulators (h-independent x-part of the dot)
    v2f a0n, a1n;
    {
        const v2f xv0 = { xb[0].x, xb[0].y };
        a0n = vfma(xv0, WX0, B0);
        a1n = vfma(xv0, WX1, B1);
    }

    for (int s = 0; s < SEQ; s += PF) {
#pragma unroll
        for (int p = 0; p < PF; ++p) {
            v2f a0 = a0n, a1 = a1n;   // init was precomputed in a trans gap

            // ---- h-gather: P_m = (h_{u^m}, h_{u^m^7}); 7 DPPs total
            v2f P0; P0.x = h; P0.y = rot<DPP_HMIR>(h);
            const v2f P1 = dpp2<DPP_X1>(P0);
            const v2f P2 = dpp2<DPP_X2>(P0);
            const v2f P3 = dpp2<DPP_X3>(P0);

            // ---- two packed split-dots (one per owned row)
            a0 = vfma(P0, W0[0], a0);  a1 = vfma(P0, W1[0], a1);
            a0 = vfma(P1, W0[1], a0);  a1 = vfma(P1, W1[1], a1);
            a0 = vfma(P2, W0[2], a0);  a1 = vfma(P2, W1[2], a1);
            a0 = vfma(P3, W0[3], a0);  a1 = vfma(P3, W1[3], a1);
            const float pre0 = a0.x + a0.y;            // already scaled
            const float pre1 = a1.x + a1.y;

            // ---- gate activations
            const float e0 = __builtin_amdgcn_exp2f(pre0);
            const float e1 = __builtin_amdgcn_exp2f(pre1);

            // [gap-fill: x prefetch for slot p, independent of everything]
            const int sn = (s + p + PF) & (SEQ - 1);   // uniform wrap
            xb[p] = xp2[sn * BATCH + b];

            const float r0 = __builtin_amdgcn_rcpf(e0 + 1.0f);
            const float r1 = __builtin_amdgcn_rcpf(e1 + 1.0f);
            const float act0 = r0 * tm0;                        // gi | gf
            const float act1 = __builtin_fmaf(r1, 2.0f, addc1); // gg | go2

            // ---- local product + 3 bank-masked ror8 exchanges (all-lane)
            const float pp  = act0 * act1;                // hf0: gi*gg
            const float gf  = ror8_keep<0x3>(act0, act0); // all: sigma_f
            const float go2 = ror8_keep<0x3>(act1, act1); // all: 2*sigma_o
            const float ig  = ror8_keep<0xC>(pp, pp);     // all: gi*gg

            // ---- c/h update in ALL lanes (h replicated by construction)
            c = __builtin_fmaf(gf, c, ig);             // scaled-c recurrence
            const float e2 = __builtin_amdgcn_exp2f(c);

            // [gap-fill inside the c-exp2 shadow: next-step x-init + ngo]
            const float2 xcn = xb[(p + 1) & (PF - 1)];
            const v2f xvn = { xcn.x, xcn.y };
            a0n = vfma(xvn, WX0, B0);
            a1n = vfma(xvn, WX1, B1);
            const float ngo = go2 * -0.5f;

            const float r2 = __builtin_amdgcn_rcpf(e2 + 1.0f);
            h = __builtin_fmaf(go2, r2, ngo);          // h = 2sig*r - sig
        }
    }

    if (!hf) out[b * 8 + u] = h;
}

extern "C" void kernel_launch(void* const* d_in, const int* in_sizes, int n_in,
                              void* d_out, int out_size, void* d_ws, size_t ws_size,
                              hipStream_t stream) {
    const float* x   = (const float*)d_in[0];
    const float* h0  = (const float*)d_in[1];
    const float* c0  = (const float*)d_in[2];
    const float* Wih = (const float*)d_in[3];
    const float* Whh = (const float*)d_in[4];
    const float* bih = (const float*)d_in[5];
    const float* bhh = (const float*)d_in[6];
    float* out = (float*)d_out;

    dim3 grid(BATCH / 16);   // 256 blocks -> 1 block/CU on all 256 CUs
    dim3 block(256);         // 4 waves/block -> 1 wave/SIMD (full chip)
    hipLaunchKernelGGL(lstm_kernel, grid, block, 0, stream,
                       x, h0, c0, Wih, Whh, bih, bhh, out);
}